// Round 8
// baseline (185.423 us; speedup 1.0000x reference)
//
#include <hip/hip_runtime.h>
#include <stdint.h>

#define B_ROWS 4096
#define N_ROWS 8192
#define D_DIM  1024
#define NRB    64          // 8192 / 128 row-blocks
#define NCB    32          // 8192 / 256 col-blocks
#define NBLKS  1056        // sum_c min(2c+2,64) : tiles with r <= 2c+1
#define XCDQ   132         // 1056 / 8, exact -> bijective XCD chunk

typedef __attribute__((ext_vector_type(8))) short bf16x8;
typedef __attribute__((ext_vector_type(4))) float f32x4;

// round-to-nearest-even f32 -> bf16
static __device__ __forceinline__ unsigned short f2bf(float f) {
  uint32_t u = __float_as_uint(f);
  u += 0x7fff + ((u >> 16) & 1);
  return (unsigned short)(u >> 16);
}

static __device__ __forceinline__ void async_copy16(const unsigned short* g, unsigned short* l) {
  __builtin_amdgcn_global_load_lds(
      (const __attribute__((address_space(1))) unsigned int*)g,
      (__attribute__((address_space(3))) unsigned int*)l, 16, 0, 0);
}

// raw workgroup barrier: does NOT drain vmcnt (unlike __syncthreads) so
// prefetch global_load_lds stay in flight across it.
static __device__ __forceinline__ void wg_barrier() {
  asm volatile("" ::: "memory");
  __builtin_amdgcn_s_barrier();
  asm volatile("" ::: "memory");
}

// One block per row: L2-normalize, cast to bf16, and zero rowsum.
__global__ __launch_bounds__(256) void normalize_kernel(
    const float* __restrict__ f1, const float* __restrict__ f2,
    unsigned short* __restrict__ F, float* __restrict__ rowsum) {
  const int row = blockIdx.x;
  const int tid = threadIdx.x;
  const float* src = (row < B_ROWS) ? (f1 + (size_t)row * D_DIM)
                                    : (f2 + (size_t)(row - B_ROWS) * D_DIM);
  float4 v = ((const float4*)src)[tid];
  float ss = v.x * v.x + v.y * v.y + v.z * v.z + v.w * v.w;
#pragma unroll
  for (int m = 1; m < 64; m <<= 1) ss += __shfl_xor(ss, m, 64);
  __shared__ float red[4];
  if ((tid & 63) == 0) red[tid >> 6] = ss;
  __syncthreads();
  ss = red[0] + red[1] + red[2] + red[3];
  const float invn = 1.0f / fmaxf(sqrtf(ss), 1e-12f);
  ushort4 o;
  o.x = f2bf(v.x * invn); o.y = f2bf(v.y * invn);
  o.z = f2bf(v.z * invn); o.w = f2bf(v.w * invn);
  ((ushort4*)(F + (size_t)row * D_DIM))[tid] = o;
  if (tid == 0) rowsum[row] = 0.0f;
}

// Fused Gram-GEMM + exp-sum epilogue over 128x256 RECT tiles covering the
// upper triangle (keep tile (r,c) iff r <= 2c+1; every unordered pair
// (i<j) lives in exactly one kept tile; mask e by j>i). 4 waves (2x2),
// each wave 64x128 (m=4 x n=8 MFMA grid): 12 ds_read_b128 -> 32 MFMA per
// K-step = 2.67 MFMA/read (was 2.0) -> LDS-bank cap rises ~41%->~55%.
// R7 scheduler verbatim: TRIPLE-buffered LDS (72 KiB, 2 blocks/CU),
// 2-step-deep counted vmcnt(6) pipeline, one barrier per K-step.
// 1056 blocks = 8 XCDs x 132 = 2.06 dispatch rounds.
__global__ __launch_bounds__(256, 2) void simloss_kernel(
    const unsigned short* __restrict__ F, float* __restrict__ rowsum,
    float* __restrict__ pos) {
  __shared__ unsigned short lA[3][128 * 32];   // 3 x 8 KiB
  __shared__ unsigned short lB[3][256 * 32];   // 3 x 16 KiB

  // --- decode slot -> (row-block r, col-block c), column-major for L2
  // locality (a column's 512 KB B-panel stays hot across its tiles) ---
  int s = (blockIdx.x & 7) * XCDQ + (blockIdx.x >> 3);
  int c = 0;
  for (;;) {
    const int nr = (2 * c + 2 < 64) ? 2 * c + 2 : 64;
    if (s < nr) break;
    s -= nr; ++c;
  }
  const int r = s;

  const int tid  = threadIdx.x;
  const int lane = tid & 63;
  const int wv   = __builtin_amdgcn_readfirstlane(tid >> 6);
  const int waveRow = wv >> 1;   // 0..1 (64-row granule)
  const int waveCol = wv & 1;    // 0..1 (128-col granule)
  const int q   = lane >> 4;
  const int l16 = lane & 15;

  const int iBase = r * 128;
  const int jBase = c * 256;
  const unsigned short* __restrict__ GA = F + (size_t)iBase * D_DIM;
  const unsigned short* __restrict__ GB = F + (size_t)jBase * D_DIM;

  f32x4 acc[4][8];
#pragma unroll
  for (int a = 0; a < 4; ++a)
#pragma unroll
    for (int b = 0; b < 8; ++b) acc[a][b] = (f32x4){0.f, 0.f, 0.f, 0.f};

  // Panel row rr (x 32 cols bf16) = 4 chunks of 16 B.
  // LDS chunk lc = rr*4 + cc holds global chunk cc ^ ((rr>>1)&3)
  // (bank-spread XOR; pre-swizzled global source, linear LDS dest,
  //  same XOR on read). A: 512 chunks (2/thread), B: 1024 (4/thread).
#define STAGE(BUFI, K0)                                                      \
  {                                                                          \
    _Pragma("unroll") for (int it = 0; it < 2; ++it) {                       \
      const int lc = it * 256 + tid;                                         \
      const int rr = lc >> 2;                                                \
      const int gc = (lc & 3) ^ ((rr >> 1) & 3);                             \
      const size_t goff = (size_t)rr * D_DIM + (K0) + gc * 8;                \
      async_copy16(GA + goff, &lA[BUFI][lc * 8]);                            \
    }                                                                        \
    _Pragma("unroll") for (int it = 0; it < 4; ++it) {                       \
      const int lc = it * 256 + tid;                                         \
      const int rr = lc >> 2;                                                \
      const int gc = (lc & 3) ^ ((rr >> 1) & 3);                             \
      const size_t goff = (size_t)rr * D_DIM + (K0) + gc * 8;                \
      async_copy16(GB + goff, &lB[BUFI][lc * 8]);                            \
    }                                                                        \
  }

  // One K-step (K=32): 12 ds_read_b128 + 32 MFMA per wave.
#define STEP(BUFI)                                                           \
  {                                                                          \
    bf16x8 af[4], bfr[8];                                                    \
    _Pragma("unroll") for (int mi = 0; mi < 4; ++mi) {                       \
      const int rr = waveRow * 64 + mi * 16 + l16;                           \
      const int ch = rr * 4 + (q ^ ((rr >> 1) & 3));                         \
      af[mi] = *(const bf16x8*)&lA[BUFI][ch * 8];                            \
    }                                                                        \
    _Pragma("unroll") for (int ni = 0; ni < 8; ++ni) {                       \
      const int rr = waveCol * 128 + ni * 16 + l16;                          \
      const int ch = rr * 4 + (q ^ ((rr >> 1) & 3));                         \
      bfr[ni] = *(const bf16x8*)&lB[BUFI][ch * 8];                           \
    }                                                                        \
    _Pragma("unroll") for (int mi = 0; mi < 4; ++mi)                         \
      _Pragma("unroll") for (int ni = 0; ni < 8; ++ni)                       \
        acc[mi][ni] = __builtin_amdgcn_mfma_f32_16x16x32_bf16(               \
            af[mi], bfr[ni], acc[mi][ni], 0, 0, 0);                          \
  }

  // prologue: stage K-steps 0 and 1 (12 loads/thread in flight)
  STAGE(0, 0)
  STAGE(1, 32)

  // main loop: 32 K-steps, one barrier + one counted vmcnt each.
  // vmcnt(6) drains stage t only (stage t+1's 6 loads stay in flight).
#pragma unroll 1
  for (int t = 0; t < 32; ++t) {
    if (t == 31) { asm volatile("s_waitcnt vmcnt(0)" ::: "memory"); }
    else         { asm volatile("s_waitcnt vmcnt(6)" ::: "memory"); }
    wg_barrier();
    if (t < 30) { STAGE((t + 2) % 3, (t + 2) * 32) }
    STEP(t % 3)
  }
#undef STEP
#undef STAGE

  // ---- epilogue ----
  // sim = 10*dot; e = exp(sim-10) for j>i only (each unordered pair is in
  // exactly one kept tile). Row-reduce -> rowsum[i]; col-reduce -> rowsum[j].
  float colAcc[8] = {0.f, 0.f, 0.f, 0.f, 0.f, 0.f, 0.f, 0.f};

#pragma unroll
  for (int mi = 0; mi < 4; ++mi) {
#pragma unroll
    for (int reg = 0; reg < 4; ++reg) {
      const int i = iBase + waveRow * 64 + mi * 16 + q * 4 + reg;
      float s2 = 0.0f;
#pragma unroll
      for (int ni = 0; ni < 8; ++ni) {
        const int j = jBase + waveCol * 128 + ni * 16 + l16;
        const float sim = acc[mi][ni][reg] * 10.0f;
        const float e = (j > i) ? __expf(sim - 10.0f) : 0.0f;
        s2 += e;
        colAcc[ni] += e;
        if (i < B_ROWS && j == i + B_ROWS) pos[i] = sim;
      }
      // reduce across the 16 lanes (same q, varying l16) sharing row i
#pragma unroll
      for (int m = 1; m < 16; m <<= 1) s2 += __shfl_xor(s2, m, 64);
      if (l16 == 0) atomicAdd(&rowsum[i], s2);
    }
  }

  // column sums: reduce across quads (lanes sharing l16); q==0 lanes hold
  // per-column totals for j = jBase + waveCol*128 + ni*16 + l16
#pragma unroll
  for (int ni = 0; ni < 8; ++ni) {
    float cs = colAcc[ni];
    cs += __shfl_xor(cs, 16, 64);
    cs += __shfl_xor(cs, 32, 64);
    if (q == 0) {
      const int j = jBase + waveCol * 128 + ni * 16 + l16;
      atomicAdd(&rowsum[j], cs);
    }
  }
}

__global__ __launch_bounds__(1024) void finalize_kernel(
    const float* __restrict__ rowsum, const float* __restrict__ pos,
    float* __restrict__ out) {
  const int tid = threadIdx.x;
  float a = 0.0f;
  for (int i = tid; i < N_ROWS; i += 1024)
    a += logf(rowsum[i]) + 10.0f - pos[i & (B_ROWS - 1)];
#pragma unroll
  for (int m = 1; m < 64; m <<= 1) a += __shfl_xor(a, m, 64);
  __shared__ float red[16];
  if ((tid & 63) == 0) red[tid >> 6] = a;
  __syncthreads();
  if (tid == 0) {
    float t = 0.0f;
#pragma unroll
    for (int w = 0; w < 16; ++w) t += red[w];
    out[0] = t * (1.0f / N_ROWS);
  }
}

extern "C" void kernel_launch(void* const* d_in, const int* in_sizes, int n_in,
                              void* d_out, int out_size, void* d_ws, size_t ws_size,
                              hipStream_t stream) {
  const float* f1 = (const float*)d_in[0];
  const float* f2 = (const float*)d_in[1];
  unsigned short* F = (unsigned short*)d_ws;                          // 16 MiB bf16 normalized features
  float* rowsum = (float*)((char*)d_ws + (size_t)N_ROWS * D_DIM * 2); // 32 KiB
  float* pos    = rowsum + N_ROWS;                                    // 16 KiB used (i < B_ROWS)
  float* out    = (float*)d_out;

  hipLaunchKernelGGL(normalize_kernel, dim3(N_ROWS), dim3(256), 0, stream, f1, f2, F, rowsum);
  hipLaunchKernelGGL(simloss_kernel, dim3(NBLKS), dim3(256), 0, stream, F, rowsum, pos);
  hipLaunchKernelGGL(finalize_kernel, dim3(1), dim3(1024), 0, stream, rowsum, pos, out);
}

// Round 9
// 150.391 us; speedup vs baseline: 1.2329x; 1.2329x over previous
//
#include <hip/hip_runtime.h>
#include <stdint.h>

#define B_ROWS 4096
#define N_ROWS 8192
#define D_DIM  1024
#define NBLK   64          // 8192 / 128 tile blocks per dim
#define NTRI   2080        // 64*65/2 upper-triangular tiles
#define XCDQ   260         // 2080 / 8, exact -> bijective XCD chunk

typedef __attribute__((ext_vector_type(4))) float f32x4;

static __device__ __forceinline__ void async_copy16(const unsigned char* g, unsigned char* l) {
  __builtin_amdgcn_global_load_lds(
      (const __attribute__((address_space(1))) unsigned int*)g,
      (__attribute__((address_space(3))) unsigned int*)l, 16, 0, 0);
}

// raw workgroup barrier: does NOT drain vmcnt (unlike __syncthreads) so
// prefetch global_load_lds stay in flight across it.
static __device__ __forceinline__ void wg_barrier() {
  asm volatile("" ::: "memory");
  __builtin_amdgcn_s_barrier();
  asm volatile("" ::: "memory");
}

// One block per row: L2-normalize, scale by 16, quantize to OCP fp8 e4m3
// (HW cvt, self-consistent with the fp8 MFMA), zero rowsum.
// sim is recovered in the GEMM epilogue as acc * 10/256.
__global__ __launch_bounds__(256) void normalize_kernel(
    const float* __restrict__ f1, const float* __restrict__ f2,
    unsigned char* __restrict__ F8, float* __restrict__ rowsum) {
  const int row = blockIdx.x;
  const int tid = threadIdx.x;
  const float* src = (row < B_ROWS) ? (f1 + (size_t)row * D_DIM)
                                    : (f2 + (size_t)(row - B_ROWS) * D_DIM);
  float4 v = ((const float4*)src)[tid];
  float ss = v.x * v.x + v.y * v.y + v.z * v.z + v.w * v.w;
#pragma unroll
  for (int m = 1; m < 64; m <<= 1) ss += __shfl_xor(ss, m, 64);
  __shared__ float red[4];
  if ((tid & 63) == 0) red[tid >> 6] = ss;
  __syncthreads();
  ss = red[0] + red[1] + red[2] + red[3];
  const float s16 = 16.0f / fmaxf(sqrtf(ss), 1e-12f);   // scale into e4m3 sweet band
  int w = 0;
  w = __builtin_amdgcn_cvt_pk_fp8_f32(v.x * s16, v.y * s16, w, 0);  // bytes 0,1
  w = __builtin_amdgcn_cvt_pk_fp8_f32(v.z * s16, v.w * s16, w, 1);  // bytes 2,3
  ((int*)(F8 + (size_t)row * D_DIM))[tid] = w;
  if (tid == 0) rowsum[row] = 0.0f;
}

// Fused Gram-GEMM (fp8 e4m3) + exp-sum epilogue over UPPER-TRIANGULAR
// 128x128 tiles. R7 structure preserved exactly (4 waves 2x2, triple
// buffer, counted vmcnt(4), one barrier/K-step, supertile-column L2
// schedule, 3 blocks/CU) with all byte counts HALVED by fp8:
// BK=64 (16 KB/buffer, 48 KB LDS), 16 K-steps (was 32), per wave/step
// 16 ds_read_b64 -> 32 mfma_f32_16x16x32_fp8_fp8.
__global__ __launch_bounds__(256, 3) void simloss_kernel(
    const unsigned char* __restrict__ F8, float* __restrict__ rowsum,
    float* __restrict__ pos) {
  __shared__ __align__(16) unsigned char lA[3][128 * 64];   // 3 x 8 KiB
  __shared__ __align__(16) unsigned char lB[3][128 * 64];   // 3 x 8 KiB

  // --- L2-locality supertile scheduling (8x8 tiles per supertile) ---
  // chunked bijective XCD remap: XCD x works slots [260x, 260x+260)
  int s = (blockIdx.x & 7) * XCDQ + (blockIdx.x >> 3);
  // supertile column SJ: col SJ holds 64*SJ + 36 tiles (sum = 2080)
  int SJ = 0;
  for (;;) { const int c = 64 * SJ + 36; if (s < c) break; s -= c; ++SJ; }
  int SI = 0;
  while (SI < SJ && s >= 64) { s -= 64; ++SI; }
  int di, dj;
  if (SI < SJ) {            // off-diagonal supertile: dj-major 8-tile groups
    dj = s >> 3; di = s & 7;
  } else {                  // diagonal supertile: upper 36 tiles, dj-major
    dj = 0; while (s > dj) { s -= (dj + 1); ++dj; } di = s;
  }
  const int bi = SI * 8 + di;
  const int bj = SJ * 8 + dj;

  const int tid  = threadIdx.x;
  const int lane = tid & 63;
  const int wv   = __builtin_amdgcn_readfirstlane(tid >> 6);
  const int waveRow = wv >> 1;   // 0..1
  const int waveCol = wv & 1;    // 0..1
  const int q   = lane >> 4;
  const int l16 = lane & 15;

  const int iBase = bi * 128;
  const int jBase = bj * 128;
  const unsigned char* __restrict__ GA = F8 + (size_t)iBase * D_DIM;
  const unsigned char* __restrict__ GB = F8 + (size_t)jBase * D_DIM;

  f32x4 acc[4][4];
#pragma unroll
  for (int a = 0; a < 4; ++a)
#pragma unroll
    for (int b = 0; b < 4; ++b) acc[a][b] = (f32x4){0.f, 0.f, 0.f, 0.f};

  // Panel row rr (128 rows x 64 fp8 bytes) = 4 chunks of 16 B.
  // LDS chunk lc = rr*4 + pc holds global chunk pc ^ ((rr>>1)&3)
  // (bank-spread XOR; pre-swizzled global SOURCE, linear LDS dest (rule
  //  21: global_load_lds dest must be linear in lane), same XOR on read).
#define STAGE(BUFI, K0)                                                      \
  {                                                                          \
    _Pragma("unroll") for (int it = 0; it < 2; ++it) {                       \
      const int lc = it * 256 + tid;                                         \
      const int rr = lc >> 2;                                                \
      const int gc = (lc & 3) ^ ((rr >> 1) & 3);                             \
      const size_t goff = (size_t)rr * D_DIM + (K0) + gc * 16;               \
      async_copy16(GA + goff, &lA[BUFI][lc * 16]);                           \
    }                                                                        \
    _Pragma("unroll") for (int it = 0; it < 2; ++it) {                       \
      const int lc = it * 256 + tid;                                         \
      const int rr = lc >> 2;                                                \
      const int gc = (lc & 3) ^ ((rr >> 1) & 3);                             \
      const size_t goff = (size_t)rr * D_DIM + (K0) + gc * 16;               \
      async_copy16(GB + goff, &lB[BUFI][lc * 16]);                           \
    }                                                                        \
  }

  // One K-step (K=64): 16 ds_read_b64 + 32 MFMA per wave.
  // Lane (q,l16) khalf h needs global bytes [32h + 8q, 32h + 8q + 8) of its
  // row: chunk = 2h + (q>>1) (XOR-swizzled), sub-offset (q&1)*8.
#define STEP(BUFI)                                                           \
  {                                                                          \
    long aF[4][2], bF[4][2];                                                 \
    _Pragma("unroll") for (int mi = 0; mi < 4; ++mi) {                       \
      const int rr  = waveRow * 64 + mi * 16 + l16;                          \
      const int swz = (rr >> 1) & 3;                                         \
      const int base = rr * 64 + ((q & 1) << 3);                             \
      aF[mi][0] = *(const long*)&lA[BUFI][base + ((((q >> 1)    ) ^ swz) << 4)]; \
      aF[mi][1] = *(const long*)&lA[BUFI][base + ((((q >> 1) + 2) ^ swz) << 4)]; \
    }                                                                        \
    _Pragma("unroll") for (int ni = 0; ni < 4; ++ni) {                       \
      const int rr  = waveCol * 64 + ni * 16 + l16;                          \
      const int swz = (rr >> 1) & 3;                                         \
      const int base = rr * 64 + ((q & 1) << 3);                             \
      bF[ni][0] = *(const long*)&lB[BUFI][base + ((((q >> 1)    ) ^ swz) << 4)]; \
      bF[ni][1] = *(const long*)&lB[BUFI][base + ((((q >> 1) + 2) ^ swz) << 4)]; \
    }                                                                        \
    _Pragma("unroll") for (int mi = 0; mi < 4; ++mi)                         \
      _Pragma("unroll") for (int ni = 0; ni < 4; ++ni) {                     \
        acc[mi][ni] = __builtin_amdgcn_mfma_f32_16x16x32_fp8_fp8(            \
            aF[mi][0], bF[ni][0], acc[mi][ni], 0, 0, 0);                     \
        acc[mi][ni] = __builtin_amdgcn_mfma_f32_16x16x32_fp8_fp8(            \
            aF[mi][1], bF[ni][1], acc[mi][ni], 0, 0, 0);                     \
      }                                                                      \
  }

  // prologue: stage K-steps 0 and 1 (8 loads/thread in flight)
  STAGE(0, 0)
  STAGE(1, 64)

  // main loop: 16 K-steps, one barrier + one counted vmcnt each.
  // vmcnt(4) drains stage t only (stage t+1's 4 loads stay in flight).
#pragma unroll 1
  for (int t = 0; t < 16; ++t) {
    if (t == 15) { asm volatile("s_waitcnt vmcnt(0)" ::: "memory"); }
    else         { asm volatile("s_waitcnt vmcnt(4)" ::: "memory"); }
    wg_barrier();
    if (t < 14) { STAGE((t + 2) % 3, (t + 2) * 64) }
    STEP(t % 3)
  }
#undef STEP
#undef STAGE

  // ---- epilogue ----
  // features were scaled by 16 -> acc = 256 * dot; sim = 10*dot = acc/25.6.
  // e = exp(sim-10) excluding diagonal. Row-reduce -> rowsum[i]; off-diag
  // tiles also column-reduce -> rowsum[j].
  const bool offdiag = (bi != bj);
  float colAcc[4] = {0.f, 0.f, 0.f, 0.f};

#pragma unroll
  for (int mi = 0; mi < 4; ++mi) {
#pragma unroll
    for (int reg = 0; reg < 4; ++reg) {
      const int i = iBase + waveRow * 64 + mi * 16 + q * 4 + reg;
      float s2 = 0.0f;
#pragma unroll
      for (int ni = 0; ni < 4; ++ni) {
        const int j = jBase + waveCol * 64 + ni * 16 + l16;
        const float sim = acc[mi][ni][reg] * (10.0f / 256.0f);
        const float e = (j == i) ? 0.0f : __expf(sim - 10.0f);
        s2 += e;
        colAcc[ni] += e;
        if (i < B_ROWS && j == i + B_ROWS) pos[i] = sim;
      }
      // reduce across the 16 lanes (same q, varying l16) sharing row i
#pragma unroll
      for (int m = 1; m < 16; m <<= 1) s2 += __shfl_xor(s2, m, 64);
      if (l16 == 0) atomicAdd(&rowsum[i], s2);
    }
  }

  if (offdiag) {
    // column sums: reduce across quads (lanes sharing l16); q==0 lanes hold
    // per-column totals for j = jBase + waveCol*64 + ni*16 + l16
#pragma unroll
    for (int ni = 0; ni < 4; ++ni) {
      float c = colAcc[ni];
      c += __shfl_xor(c, 16, 64);
      c += __shfl_xor(c, 32, 64);
      if (q == 0) {
        const int j = jBase + waveCol * 64 + ni * 16 + l16;
        atomicAdd(&rowsum[j], c);
      }
    }
  }
}

__global__ __launch_bounds__(1024) void finalize_kernel(
    const float* __restrict__ rowsum, const float* __restrict__ pos,
    float* __restrict__ out) {
  const int tid = threadIdx.x;
  float a = 0.0f;
  for (int i = tid; i < N_ROWS; i += 1024)
    a += logf(rowsum[i]) + 10.0f - pos[i & (B_ROWS - 1)];
#pragma unroll
  for (int m = 1; m < 64; m <<= 1) a += __shfl_xor(a, m, 64);
  __shared__ float red[16];
  if ((tid & 63) == 0) red[tid >> 6] = a;
  __syncthreads();
  if (tid == 0) {
    float t = 0.0f;
#pragma unroll
    for (int w = 0; w < 16; ++w) t += red[w];
    out[0] = t * (1.0f / N_ROWS);
  }
}

extern "C" void kernel_launch(void* const* d_in, const int* in_sizes, int n_in,
                              void* d_out, int out_size, void* d_ws, size_t ws_size,
                              hipStream_t stream) {
  const float* f1 = (const float*)d_in[0];
  const float* f2 = (const float*)d_in[1];
  unsigned char* F8 = (unsigned char*)d_ws;                       // 8 MiB fp8 features (x16 scale)
  float* rowsum = (float*)((char*)d_ws + (size_t)N_ROWS * D_DIM); // 32 KiB
  float* pos    = rowsum + N_ROWS;                                // 16 KiB used (i < B_ROWS)
  float* out    = (float*)d_out;

  hipLaunchKernelGGL(normalize_kernel, dim3(N_ROWS), dim3(256), 0, stream, f1, f2, F8, rowsum);
  hipLaunchKernelGGL(simloss_kernel, dim3(NTRI), dim3(256), 0, stream, F8, rowsum, pos);
  hipLaunchKernelGGL(finalize_kernel, dim3(1), dim3(1024), 0, stream, rowsum, pos, out);
}

// Round 10
// 144.685 us; speedup vs baseline: 1.2816x; 1.0394x over previous
//
#include <hip/hip_runtime.h>
#include <stdint.h>

#define B_ROWS 4096
#define N_ROWS 8192
#define D_DIM  1024
#define NBLK   64          // 8192 / 128 tile blocks per dim
#define NTRI   2080        // 64*65/2 upper-triangular tiles
#define XCDQ   260         // 2080 / 8, exact -> bijective XCD chunk

typedef __attribute__((ext_vector_type(4))) float f32x4;
typedef __attribute__((ext_vector_type(2))) long longx2;

static __device__ __forceinline__ void async_copy16(const unsigned char* g, unsigned char* l) {
  __builtin_amdgcn_global_load_lds(
      (const __attribute__((address_space(1))) unsigned int*)g,
      (__attribute__((address_space(3))) unsigned int*)l, 16, 0, 0);
}

// raw workgroup barrier: does NOT drain vmcnt (unlike __syncthreads) so
// prefetch global_load_lds stay in flight across it.
static __device__ __forceinline__ void wg_barrier() {
  asm volatile("" ::: "memory");
  __builtin_amdgcn_s_barrier();
  asm volatile("" ::: "memory");
}

// One block per row: L2-normalize, scale by 16, quantize to OCP fp8 e4m3,
// and store K-INTERLEAVED: within each 64-byte K-group, byte position
// g = 16q + 8h + off for k = 32h + 8q + off. This makes each MFMA lane's
// two 8-byte k-pieces (k in [8q,8q+8) and [32+8q,32+8q+8)) a contiguous
// 16 B chunk -> simloss reads ds_read_b128 (conflict-free 2-way) instead
// of the 4-way-conflicting ds_read_b64 pair (R9: 8.5M conflict cycles).
__global__ __launch_bounds__(256) void normalize_kernel(
    const float* __restrict__ f1, const float* __restrict__ f2,
    unsigned char* __restrict__ F8, float* __restrict__ rowsum) {
  const int row = blockIdx.x;
  const int tid = threadIdx.x;
  const float* src = (row < B_ROWS) ? (f1 + (size_t)row * D_DIM)
                                    : (f2 + (size_t)(row - B_ROWS) * D_DIM);
  float4 v = ((const float4*)src)[tid];
  float ss = v.x * v.x + v.y * v.y + v.z * v.z + v.w * v.w;
#pragma unroll
  for (int m = 1; m < 64; m <<= 1) ss += __shfl_xor(ss, m, 64);
  __shared__ float red[4];
  if ((tid & 63) == 0) red[tid >> 6] = ss;
  __syncthreads();
  ss = red[0] + red[1] + red[2] + red[3];
  const float s16 = 16.0f / fmaxf(sqrtf(ss), 1e-12f);   // scale into e4m3 sweet band
  int w = 0;
  w = __builtin_amdgcn_cvt_pk_fp8_f32(v.x * s16, v.y * s16, w, 0);  // bytes 0,1
  w = __builtin_amdgcn_cvt_pk_fp8_f32(v.z * s16, v.w * s16, w, 1);  // bytes 2,3
  // thread tid covers k = 4*tid..4*tid+3; within its 64-byte group:
  // h=(tid>>3)&1, q=(tid>>1)&3, off=4*(tid&1)
  const int idx = (tid >> 4) * 16 + ((tid >> 1) & 3) * 4 +
                  ((tid >> 3) & 1) * 2 + (tid & 1);
  ((int*)(F8 + (size_t)row * D_DIM))[idx] = w;
  if (tid == 0) rowsum[row] = 0.0f;
}

// Fused Gram-GEMM (fp8 e4m3) + exp-sum epilogue over UPPER-TRIANGULAR
// 128x128 tiles. R9 structure (4 waves 2x2, triple buffer, counted
// vmcnt(4), one barrier/K-step, supertile-column L2 schedule) with the
// K-interleaved layout: per wave/step 8 ds_read_b128 (was 16 b64, 4-way
// conflicted) -> 32 mfma_f32_16x16x32_fp8_fp8.
__global__ __launch_bounds__(256, 3) void simloss_kernel(
    const unsigned char* __restrict__ F8, float* __restrict__ rowsum,
    float* __restrict__ pos) {
  __shared__ __align__(16) unsigned char lA[3][128 * 64];   // 3 x 8 KiB
  __shared__ __align__(16) unsigned char lB[3][128 * 64];   // 3 x 8 KiB

  // --- L2-locality supertile scheduling (8x8 tiles per supertile) ---
  // chunked bijective XCD remap: XCD x works slots [260x, 260x+260)
  int s = (blockIdx.x & 7) * XCDQ + (blockIdx.x >> 3);
  // supertile column SJ: col SJ holds 64*SJ + 36 tiles (sum = 2080)
  int SJ = 0;
  for (;;) { const int c = 64 * SJ + 36; if (s < c) break; s -= c; ++SJ; }
  int SI = 0;
  while (SI < SJ && s >= 64) { s -= 64; ++SI; }
  int di, dj;
  if (SI < SJ) {            // off-diagonal supertile: dj-major 8-tile groups
    dj = s >> 3; di = s & 7;
  } else {                  // diagonal supertile: upper 36 tiles, dj-major
    dj = 0; while (s > dj) { s -= (dj + 1); ++dj; } di = s;
  }
  const int bi = SI * 8 + di;
  const int bj = SJ * 8 + dj;

  const int tid  = threadIdx.x;
  const int lane = tid & 63;
  const int wv   = __builtin_amdgcn_readfirstlane(tid >> 6);
  const int waveRow = wv >> 1;   // 0..1
  const int waveCol = wv & 1;    // 0..1
  const int q   = lane >> 4;
  const int l16 = lane & 15;

  const int iBase = bi * 128;
  const int jBase = bj * 128;
  const unsigned char* __restrict__ GA = F8 + (size_t)iBase * D_DIM;
  const unsigned char* __restrict__ GB = F8 + (size_t)jBase * D_DIM;

  f32x4 acc[4][4];
#pragma unroll
  for (int a = 0; a < 4; ++a)
#pragma unroll
    for (int b = 0; b < 4; ++b) acc[a][b] = (f32x4){0.f, 0.f, 0.f, 0.f};

  // Panel row rr (128 rows x 64 fp8 bytes) = 4 chunks of 16 B.
  // LDS chunk lc = rr*4 + pc holds global chunk pc ^ ((rr>>1)&3)
  // (bank-spread XOR; pre-swizzled global SOURCE, linear LDS dest (rule
  //  21), same XOR on read).
#define STAGE(BUFI, K0)                                                      \
  {                                                                          \
    _Pragma("unroll") for (int it = 0; it < 2; ++it) {                       \
      const int lc = it * 256 + tid;                                         \
      const int rr = lc >> 2;                                                \
      const int gc = (lc & 3) ^ ((rr >> 1) & 3);                             \
      const size_t goff = (size_t)rr * D_DIM + (K0) + gc * 16;               \
      async_copy16(GA + goff, &lA[BUFI][lc * 16]);                           \
    }                                                                        \
    _Pragma("unroll") for (int it = 0; it < 2; ++it) {                       \
      const int lc = it * 256 + tid;                                         \
      const int rr = lc >> 2;                                                \
      const int gc = (lc & 3) ^ ((rr >> 1) & 3);                             \
      const size_t goff = (size_t)rr * D_DIM + (K0) + gc * 16;               \
      async_copy16(GB + goff, &lB[BUFI][lc * 16]);                           \
    }                                                                        \
  }

  // One K-step (K=64): 8 ds_read_b128 + 32 MFMA per wave.
  // Lane (q,l16) reads the K-interleaved chunk q (16 B = both k-halves),
  // XOR-swizzled: LDS chunk = q ^ ((rr>>1)&3).
#define STEP(BUFI)                                                           \
  {                                                                          \
    longx2 aF[4], bF[4];                                                     \
    _Pragma("unroll") for (int mi = 0; mi < 4; ++mi) {                       \
      const int rr = waveRow * 64 + mi * 16 + l16;                           \
      const int ch = rr * 4 + (q ^ ((rr >> 1) & 3));                         \
      aF[mi] = *(const longx2*)&lA[BUFI][ch * 16];                           \
    }                                                                        \
    _Pragma("unroll") for (int ni = 0; ni < 4; ++ni) {                       \
      const int rr = waveCol * 64 + ni * 16 + l16;                           \
      const int ch = rr * 4 + (q ^ ((rr >> 1) & 3));                         \
      bF[ni] = *(const longx2*)&lB[BUFI][ch * 16];                           \
    }                                                                        \
    _Pragma("unroll") for (int mi = 0; mi < 4; ++mi)                         \
      _Pragma("unroll") for (int ni = 0; ni < 4; ++ni) {                     \
        acc[mi][ni] = __builtin_amdgcn_mfma_f32_16x16x32_fp8_fp8(            \
            aF[mi].x, bF[ni].x, acc[mi][ni], 0, 0, 0);                       \
        acc[mi][ni] = __builtin_amdgcn_mfma_f32_16x16x32_fp8_fp8(            \
            aF[mi].y, bF[ni].y, acc[mi][ni], 0, 0, 0);                       \
      }                                                                      \
  }

  // prologue: stage K-steps 0 and 1 (8 loads/thread in flight)
  STAGE(0, 0)
  STAGE(1, 64)

  // main loop: 16 K-steps, one barrier + one counted vmcnt each.
  // vmcnt(4) drains stage t only (stage t+1's 4 loads stay in flight).
#pragma unroll 1
  for (int t = 0; t < 16; ++t) {
    if (t == 15) { asm volatile("s_waitcnt vmcnt(0)" ::: "memory"); }
    else         { asm volatile("s_waitcnt vmcnt(4)" ::: "memory"); }
    wg_barrier();
    if (t < 14) { STAGE((t + 2) % 3, (t + 2) * 64) }
    STEP(t % 3)
  }
#undef STEP
#undef STAGE

  // ---- epilogue ----
  // features were scaled by 16 -> acc = 256 * dot; sim = 10*dot = acc/25.6.
  // e = exp(sim-10) excluding diagonal. Row-reduce -> rowsum[i]; off-diag
  // tiles also column-reduce -> rowsum[j].
  const bool offdiag = (bi != bj);
  float colAcc[4] = {0.f, 0.f, 0.f, 0.f};

#pragma unroll
  for (int mi = 0; mi < 4; ++mi) {
#pragma unroll
    for (int reg = 0; reg < 4; ++reg) {
      const int i = iBase + waveRow * 64 + mi * 16 + q * 4 + reg;
      float s2 = 0.0f;
#pragma unroll
      for (int ni = 0; ni < 4; ++ni) {
        const int j = jBase + waveCol * 64 + ni * 16 + l16;
        const float sim = acc[mi][ni][reg] * (10.0f / 256.0f);
        const float e = (j == i) ? 0.0f : __expf(sim - 10.0f);
        s2 += e;
        colAcc[ni] += e;
        if (i < B_ROWS && j == i + B_ROWS) pos[i] = sim;
      }
      // reduce across the 16 lanes (same q, varying l16) sharing row i
#pragma unroll
      for (int m = 1; m < 16; m <<= 1) s2 += __shfl_xor(s2, m, 64);
      if (l16 == 0) atomicAdd(&rowsum[i], s2);
    }
  }

  if (offdiag) {
    // column sums: reduce across quads (lanes sharing l16); q==0 lanes hold
    // per-column totals for j = jBase + waveCol*64 + ni*16 + l16
#pragma unroll
    for (int ni = 0; ni < 4; ++ni) {
      float c = colAcc[ni];
      c += __shfl_xor(c, 16, 64);
      c += __shfl_xor(c, 32, 64);
      if (q == 0) {
        const int j = jBase + waveCol * 64 + ni * 16 + l16;
        atomicAdd(&rowsum[j], c);
      }
    }
  }
}

__global__ __launch_bounds__(1024) void finalize_kernel(
    const float* __restrict__ rowsum, const float* __restrict__ pos,
    float* __restrict__ out) {
  const int tid = threadIdx.x;
  float a = 0.0f;
  for (int i = tid; i < N_ROWS; i += 1024)
    a += logf(rowsum[i]) + 10.0f - pos[i & (B_ROWS - 1)];
#pragma unroll
  for (int m = 1; m < 64; m <<= 1) a += __shfl_xor(a, m, 64);
  __shared__ float red[16];
  if ((tid & 63) == 0) red[tid >> 6] = a;
  __syncthreads();
  if (tid == 0) {
    float t = 0.0f;
#pragma unroll
    for (int w = 0; w < 16; ++w) t += red[w];
    out[0] = t * (1.0f / N_ROWS);
  }
}

extern "C" void kernel_launch(void* const* d_in, const int* in_sizes, int n_in,
                              void* d_out, int out_size, void* d_ws, size_t ws_size,
                              hipStream_t stream) {
  const float* f1 = (const float*)d_in[0];
  const float* f2 = (const float*)d_in[1];
  unsigned char* F8 = (unsigned char*)d_ws;                       // 8 MiB fp8 features (x16 scale, k-interleaved)
  float* rowsum = (float*)((char*)d_ws + (size_t)N_ROWS * D_DIM); // 32 KiB
  float* pos    = rowsum + N_ROWS;                                // 16 KiB used (i < B_ROWS)
  float* out    = (float*)d_out;

  hipLaunchKernelGGL(normalize_kernel, dim3(N_ROWS), dim3(256), 0, stream, f1, f2, F8, rowsum);
  hipLaunchKernelGGL(simloss_kernel, dim3(NTRI), dim3(256), 0, stream, F8, rowsum, pos);
  hipLaunchKernelGGL(finalize_kernel, dim3(1), dim3(1024), 0, stream, rowsum, pos, out);
}